// Round 1
// 245.362 us; speedup vs baseline: 1.0245x; 1.0245x over previous
//
#include <hip/hip_runtime.h>

// Problem constants (from reference)
constexpr int D_OUT    = 4096;
constexpr int D_IN     = 11008;
constexpr int REMAINED = 5504;
constexpr int NV       = D_IN / 4;       // 2752 float4 per weight row
constexpr int BLK      = 256;
constexpr int ROWS     = 8;              // 512 blocks -> 2/CU, all resident
constexpr int NIDX4    = REMAINED / 4;   // 1376 int4/float4 pairs
constexpr int ISLOT    = (NIDX4 + BLK - 1) / BLK;  // 6 (tid<96 uses slot 5)

// Native clang vector type: __builtin_nontemporal_load rejects HIP_vector_type.
typedef float fvec4 __attribute__((ext_vector_type(4)));

// Fused scatter+GEMV.
// Prologue ordering: (a) start the c->idx4/x4 dependent-load chain FIRST so it
// completes inside the W-prefetch window; (b) 2-deep W prefetch (16 NT loads,
// 32 MB device-wide ~5us of stream) keeps HBM saturated across both barriers;
// (c) scatter runs register->LDS only (no global latency between barriers).
__global__ __launch_bounds__(BLK, 2) void fused_gemv_kernel(
    const float* __restrict__ x,
    const fvec4* __restrict__ W,
    const float* __restrict__ bias,
    const int*   __restrict__ act_idx,
    const int*   __restrict__ cluster,
    float*       __restrict__ out)
{
    __shared__ float xd[D_IN];                 // 44032 B -> LDS caps 3/CU, grid gives 2/CU
    __shared__ float red[ROWS][BLK / 64];

    const int tid  = threadIdx.x;
    const int row0 = blockIdx.x * ROWS;
    const fvec4* w0 = W + (size_t)row0 * NV;

    // (0) scatter inputs -> registers, issued first (latency hides under W burst)
    const int c = cluster[0];
    const int4*  idx4 = (const int4*)(act_idx + (size_t)c * REMAINED);
    const fvec4* x4   = (const fvec4*)x;
    int4  idreg[ISLOT];
    fvec4 xreg[ISLOT];
    #pragma unroll
    for (int s = 0; s < ISLOT; ++s) {
        const int i = tid + s * BLK;
        if (i < NIDX4) { xreg[s] = x4[i]; idreg[s] = idx4[i]; }
    }

    // (1) 2-deep W prefetch: iterations 0 and 1 in flight during the prologue
    fvec4 wA[ROWS], wB[ROWS];
    #pragma unroll
    for (int r = 0; r < ROWS; ++r)
        wA[r] = __builtin_nontemporal_load(&w0[(size_t)r * NV + tid]);
    #pragma unroll
    for (int r = 0; r < ROWS; ++r)
        wB[r] = __builtin_nontemporal_load(&w0[(size_t)r * NV + tid + BLK]);

    // (2) zero xd with b128 writes (11 iters)
    fvec4* xdw = (fvec4*)xd;
    for (int i = tid; i < NV; i += BLK) xdw[i] = (fvec4)0.f;
    __syncthreads();                           // vmcnt(0) drain: all prefetches landed

    // (3) scatter from registers: LDS float atomics only (dups accumulate)
    #pragma unroll
    for (int s = 0; s < ISLOT; ++s) {
        const int i = tid + s * BLK;
        if (i < NIDX4) {
            atomicAdd(&xd[idreg[s].x], xreg[s].x);
            atomicAdd(&xd[idreg[s].y], xreg[s].y);
            atomicAdd(&xd[idreg[s].z], xreg[s].z);
            atomicAdd(&xd[idreg[s].w], xreg[s].w);
        }
    }
    __syncthreads();

    // (4) dense GEMV: uniform 2-deep rotating pipeline over k = tid + 256*it
    //     its 0..9 are valid for ALL threads (tid+2304+255 < 2752); it=10 masked.
    const fvec4* xd4 = (const fvec4*)xd;
    float acc[ROWS] = {};

    #define FMA8(wv, xv) do { _Pragma("unroll")                                 \
        for (int r = 0; r < ROWS; ++r)                                          \
            acc[r] = fmaf((wv)[r].x, (xv).x, fmaf((wv)[r].y, (xv).y,            \
                     fmaf((wv)[r].z, (xv).z, fmaf((wv)[r].w, (xv).w, acc[r])))); \
        } while (0)

    int kc = tid;
    #pragma unroll 1   // keep A/B slots statically indexed; no scratch spill
    for (int it = 0; it < 4; ++it) {           // consumes its 0..7, refills to it 9
        fvec4 xv0 = xd4[kc];
        FMA8(wA, xv0);
        #pragma unroll
        for (int r = 0; r < ROWS; ++r)
            wA[r] = __builtin_nontemporal_load(&w0[(size_t)r * NV + kc + 2 * BLK]);
        fvec4 xv1 = xd4[kc + BLK];
        FMA8(wB, xv1);
        #pragma unroll
        for (int r = 0; r < ROWS; ++r)
            wB[r] = __builtin_nontemporal_load(&w0[(size_t)r * NV + kc + 3 * BLK]);
        kc += 2 * BLK;
    }
    {   // kc = tid + 2048: consume it 8 (wA), it 9 (wB), masked tail it 10
        fvec4 xv0 = xd4[kc];
        FMA8(wA, xv0);
        const bool tail = (tid < NV - 10 * BLK);          // tid < 192
        if (tail) {
            #pragma unroll
            for (int r = 0; r < ROWS; ++r)
                wA[r] = __builtin_nontemporal_load(&w0[(size_t)r * NV + kc + 2 * BLK]);
        }
        fvec4 xv1 = xd4[kc + BLK];
        FMA8(wB, xv1);
        if (tail) {
            fvec4 xv2 = xd4[kc + 2 * BLK];
            FMA8(wA, xv2);
        }
    }
    #undef FMA8

    // (5) reduce: wave64 shuffle, then cross-wave via LDS
    const int lane = tid & 63;
    const int wave = tid >> 6;
    #pragma unroll
    for (int r = 0; r < ROWS; ++r) {
        float v = acc[r];
        #pragma unroll
        for (int off = 32; off > 0; off >>= 1)
            v += __shfl_down(v, off, 64);
        if (lane == 0) red[r][wave] = v;
    }
    __syncthreads();
    if (tid < ROWS) {
        float s = red[tid][0] + red[tid][1] + red[tid][2] + red[tid][3];
        out[row0 + tid] = s + bias[row0 + tid];
    }
}

extern "C" void kernel_launch(void* const* d_in, const int* in_sizes, int n_in,
                              void* d_out, int out_size, void* d_ws, size_t ws_size,
                              hipStream_t stream)
{
    const float* x       = (const float*)d_in[0];
    const float* weight  = (const float*)d_in[1];
    const float* bias    = (const float*)d_in[2];
    const int*   act_idx = (const int*)d_in[3];
    const int*   cluster = (const int*)d_in[4];
    float*       out     = (float*)d_out;

    fused_gemv_kernel<<<D_OUT / ROWS, BLK, 0, stream>>>(
        x, (const fvec4*)weight, bias, act_idx, cluster, out);
}